// Round 5
// baseline (3778.574 us; speedup 1.0000x reference)
//
#include <hip/hip_runtime.h>
#include <hip/hip_bf16.h>

#define Sd 442368      // D*H*W
#define HWc 9216
#define Wc 96
#define Hc 96
#define Dc 48

typedef unsigned short u16;
typedef unsigned int u32;
typedef __attribute__((ext_vector_type(8))) short short8;
typedef __attribute__((ext_vector_type(4))) float f32x4;
typedef __attribute__((ext_vector_type(2))) float f32x2;

static __device__ __forceinline__ u16 f2bf(float f){
    __hip_bfloat16 h = __float2bfloat16(f);
    return *reinterpret_cast<u16*>(&h);
}
static __device__ __forceinline__ u32 pk2(float a, float b){
    return ((u32)f2bf(b) << 16) | (u32)f2bf(a);
}
static __device__ __forceinline__ f32x2 unp2(u32 u){
    f32x2 r; r.x = __uint_as_float(u << 16); r.y = __uint_as_float(u & 0xffff0000u); return r;
}

static __device__ __forceinline__ short8 ldfrag_w(const float* p){
    float4 f0 = *reinterpret_cast<const float4*>(p);
    float4 f1 = *reinterpret_cast<const float4*>(p + 4);
    union { short8 s; u32 u[4]; } r;
    r.u[0] = pk2(f0.x, f0.y); r.u[1] = pk2(f0.z, f0.w);
    r.u[2] = pk2(f1.x, f1.y); r.u[3] = pk2(f1.z, f1.w);
    return r.s;
}

// ---------------- Pass A: K,V projection via MFMA, bf16 [vox][128] ----------------
#define NBLK_A 3456
__global__ __launch_bounds__(256, 2) void kv_mfma(
    const float* __restrict__ x, const float* __restrict__ qkv_w,
    const float* __restrict__ qkv_b, u16* __restrict__ KV)
{
    int bid = blockIdx.x;
    bid = (bid & 7) * (NBLK_A / 8) + (bid >> 3);
    int batch = bid / (NBLK_A / 2);
    int s0 = (bid - batch * (NBLK_A / 2)) * 256;
    int t = threadIdx.x, lane = t & 63, wv = t >> 6;
    int lo = lane & 15, hi = lane >> 4;
    __shared__ u16 L[256 * 72];

    const float* xb = x + (size_t)batch * 64 * Sd + s0;
    {
        u32 pk[32];
#pragma unroll
        for (int c = 0; c < 64; c += 2){
            float f0 = xb[(size_t)c * Sd + t];
            float f1 = xb[(size_t)(c + 1) * Sd + t];
            pk[c >> 1] = pk2(f0, f1);
        }
#pragma unroll
        for (int k = 0; k < 8; ++k){
            uint4 u; u.x = pk[k*4+0]; u.y = pk[k*4+1]; u.z = pk[k*4+2]; u.w = pk[k*4+3];
            *reinterpret_cast<uint4*>(&L[t * 72 + k * 8]) = u;
        }
    }
    // wave-local staging: thread t writes row t; wave reads rows [wv*64, wv*64+64)

    short8 af[8][2];
    f32x4  bias[8];
#pragma unroll
    for (int mt = 0; mt < 8; ++mt){
#pragma unroll
        for (int kh = 0; kh < 2; ++kh)
            af[mt][kh] = ldfrag_w(qkv_w + (size_t)(64 + mt*16 + lo) * 64 + kh*32 + hi*8);
        bias[mt] = *reinterpret_cast<const f32x4*>(qkv_b + 64 + mt*16 + hi*4);
    }

#pragma unroll
    for (int nt = 0; nt < 4; ++nt){
        int vl = wv * 64 + nt * 16 + lo;
        const u16* br = &L[vl * 72 + hi * 8];
        short8 b0 = *reinterpret_cast<const short8*>(br);
        short8 b1 = *reinterpret_cast<const short8*>(br + 32);
        u16* kvrow = KV + (size_t)(batch * Sd + s0 + vl) * 128 + hi * 4;
#pragma unroll
        for (int mt = 0; mt < 8; ++mt){
            f32x4 acc = bias[mt];
            acc = __builtin_amdgcn_mfma_f32_16x16x32_bf16(af[mt][0], b0, acc, 0, 0, 0);
            acc = __builtin_amdgcn_mfma_f32_16x16x32_bf16(af[mt][1], b1, acc, 0, 0, 0);
            uint2 st; st.x = pk2(acc[0], acc[1]); st.y = pk2(acc[2], acc[3]);
            *reinterpret_cast<uint2*>(kvrow + mt * 16) = st;
        }
    }
}

// ---------------- Pass B: two-phase no-max softmax attention, 2 threads/voxel ----------------
#define NBLK_B 6912
#define SCLOG 0.18033688011112042f   // 0.125 * log2(e)

__global__ __launch_bounds__(256, 6) void attn_fused(
    const float* __restrict__ x, const float* __restrict__ qkv_w,
    const float* __restrict__ qkv_b, const float* __restrict__ out_w,
    const float* __restrict__ out_b, const float* __restrict__ rel_pos,
    const u16* __restrict__ KV, float* __restrict__ out)
{
    int bid = blockIdx.x;
    bid = (bid & 7) * (NBLK_B / 8) + (bid >> 3);
    int batch = bid / (NBLK_B / 2);
    int s0 = (bid - batch * (NBLK_B / 2)) * 128;
    int t = threadIdx.x, lane = t & 63, wv = t >> 6;
    int lo = lane & 15, hi = lane >> 4;
    int vt = t >> 1, half = t & 1;

    __shared__ u16 Lx[128 * 72];     // x bf16 -> Q bf16 (in place) -> attn-out bf16
    __shared__ u16 Lr16[128 * 28];   // rel-logits bf16, pre-scaled by SCLOG

    const float* xb = x + (size_t)batch * 64 * Sd + s0;
    {   // stage own 32 channels of voxel vt (wave-local rows)
        u32 pk[16];
#pragma unroll
        for (int c2 = 0; c2 < 32; c2 += 2){
            float f0 = xb[(size_t)(half*32 + c2) * Sd + vt];
            float f1 = xb[(size_t)(half*32 + c2 + 1) * Sd + vt];
            pk[c2 >> 1] = pk2(f0, f1);
        }
#pragma unroll
        for (int k = 0; k < 4; ++k){
            uint4 u; u.x = pk[k*4+0]; u.y = pk[k*4+1]; u.z = pk[k*4+2]; u.w = pk[k*4+3];
            *reinterpret_cast<uint4*>(&Lx[vt * 72 + half * 32 + k * 8]) = u;
        }
    }

    {   // Q-projection MFMA; overwrite own wave's rows of Lx with Q bf16
        short8 qa[4][2];
        f32x4  qbias[4];
#pragma unroll
        for (int mt = 0; mt < 4; ++mt){
#pragma unroll
            for (int kh = 0; kh < 2; ++kh)
                qa[mt][kh] = ldfrag_w(qkv_w + (size_t)(mt*16 + lo) * 64 + kh*32 + hi*8);
            qbias[mt] = *reinterpret_cast<const f32x4*>(qkv_b + mt*16 + hi*4);
        }
#pragma unroll
        for (int nt = 0; nt < 2; ++nt){
            int vl = wv * 32 + nt * 16 + lo;
            const u16* br = &Lx[vl * 72 + hi * 8];
            short8 b0 = *reinterpret_cast<const short8*>(br);
            short8 b1 = *reinterpret_cast<const short8*>(br + 32);
#pragma unroll
            for (int mt = 0; mt < 4; ++mt){
                f32x4 acc = qbias[mt];
                acc = __builtin_amdgcn_mfma_f32_16x16x32_bf16(qa[mt][0], b0, acc, 0, 0, 0);
                acc = __builtin_amdgcn_mfma_f32_16x16x32_bf16(qa[mt][1], b1, acc, 0, 0, 0);
                uint2 st; st.x = pk2(acc[0], acc[1]); st.y = pk2(acc[2], acc[3]);
                *reinterpret_cast<uint2*>(&Lx[vl * 72 + mt * 16 + hi * 4]) = st;
            }
        }
    }

    {   // rel-logits MFMA: R(27x64 pad 32) x Q -> Lr16 bf16 (scaled by SCLOG)
        short8 ra[2][2];
#pragma unroll
        for (int mt = 0; mt < 2; ++mt){
            int o = mt * 16 + lo;
#pragma unroll
            for (int kh = 0; kh < 2; ++kh){
                float f[8];
#pragma unroll
                for (int j = 0; j < 8; ++j){
                    int k = kh * 32 + hi * 8 + j;
                    f[j] = (o < 27) ? rel_pos[k * 27 + o] : 0.f;
                }
                union { short8 s; u32 u[4]; } r;
                r.u[0] = pk2(f[0], f[1]); r.u[1] = pk2(f[2], f[3]);
                r.u[2] = pk2(f[4], f[5]); r.u[3] = pk2(f[6], f[7]);
                ra[mt][kh] = r.s;
            }
        }
        u32* Lr32 = reinterpret_cast<u32*>(Lr16);
#pragma unroll
        for (int nt = 0; nt < 2; ++nt){
            int vl = wv * 32 + nt * 16 + lo;
            const u16* br = &Lx[vl * 72 + hi * 8];
            short8 b0 = *reinterpret_cast<const short8*>(br);
            short8 b1 = *reinterpret_cast<const short8*>(br + 32);
            f32x4 a0 = {0.f, 0.f, 0.f, 0.f};
            f32x4 a1 = {0.f, 0.f, 0.f, 0.f};
            a0 = __builtin_amdgcn_mfma_f32_16x16x32_bf16(ra[0][0], b0, a0, 0, 0, 0);
            a0 = __builtin_amdgcn_mfma_f32_16x16x32_bf16(ra[0][1], b1, a0, 0, 0, 0);
            a1 = __builtin_amdgcn_mfma_f32_16x16x32_bf16(ra[1][0], b0, a1, 0, 0, 0);
            a1 = __builtin_amdgcn_mfma_f32_16x16x32_bf16(ra[1][1], b1, a1, 0, 0, 0);
            // rows hi*4+{0..3} at col vl, packed pairs -> dwords
            Lr32[vl * 14 + hi * 2 + 0] = pk2(a0[0] * SCLOG, a0[1] * SCLOG);
            Lr32[vl * 14 + hi * 2 + 1] = pk2(a0[2] * SCLOG, a0[3] * SCLOG);
            if (hi < 3){   // rows 16+hi*4+{0..3} (row 27 slot is padding, never read)
                Lr32[vl * 14 + 8 + hi * 2 + 0] = pk2(a1[0] * SCLOG, a1[1] * SCLOG);
                Lr32[vl * 14 + 8 + hi * 2 + 1] = pk2(a1[2] * SCLOG, a1[3] * SCLOG);
            }
        }
    }

    // per-thread: own half of Q, pre-scaled, as f32x2 pairs
    f32x2 q2[16];
#pragma unroll
    for (int k = 0; k < 4; ++k){
        uint4 q4 = *reinterpret_cast<const uint4*>(&Lx[vt * 72 + half * 32 + k * 8]);
        q2[k*4+0] = unp2(q4.x) * SCLOG;
        q2[k*4+1] = unp2(q4.y) * SCLOG;
        q2[k*4+2] = unp2(q4.z) * SCLOG;
        q2[k*4+3] = unp2(q4.w) * SCLOG;
    }

    int s = s0 + vt;
    int d = s / HWc; int r = s - d * HWc; int h3 = r / Wc; int w3 = r - h3 * Wc;

    int cdm = (d  > 0)      ? -HWc : 0;
    int cdp = (d  < Dc - 1) ?  HWc : 0;
    int chm = (h3 > 0)      ? -Wc  : 0;
    int chp = (h3 < Hc - 1) ?  Wc  : 0;
    int cwm = (w3 > 0)      ? -1   : 0;
    int cwp = (w3 < Wc - 1) ?  1   : 0;
    bool vdm = d  > 0, vdp = d  < Dc - 1;
    bool vhm = h3 > 0, vhp = h3 < Hc - 1;
    bool vwm = w3 > 0, vwp = w3 < Wc - 1;

    const char* KVc = reinterpret_cast<const char*>(KV);
    int kbase = (batch * Sd + s) * 256 + half * 64;
    const u16* lr = &Lr16[vt * 28];

    // ---- Phase 1: 27 independent K-dots -> p[o] (no max subtraction; logits bounded) ----
    float p[27];
#pragma unroll
    for (int o = 0; o < 27; ++o){
        const int di = o / 9 - 1, dj = (o / 3) % 3 - 1, dk = o % 3 - 1;
        int doff = (di < 0 ? cdm : di > 0 ? cdp : 0)
                 + (dj < 0 ? chm : dj > 0 ? chp : 0)
                 + (dk < 0 ? cwm : dk > 0 ? cwp : 0);
        bool valid = (di < 0 ? vdm : di > 0 ? vdp : true)
                  && (dj < 0 ? vhm : dj > 0 ? vhp : true)
                  && (dk < 0 ? vwm : dk > 0 ? vwp : true);
        const uint4* p4 = reinterpret_cast<const uint4*>(KVc + (kbase + doff * 256));
        uint4 kk[4];
#pragma unroll
        for (int k = 0; k < 4; ++k) kk[k] = p4[k];
        f32x2 dd = {0.f, 0.f};
#pragma unroll
        for (int k = 0; k < 4; ++k){
            dd += unp2(kk[k].x) * q2[k*4+0];
            dd += unp2(kk[k].y) * q2[k*4+1];
            dd += unp2(kk[k].z) * q2[k*4+2];
            dd += unp2(kk[k].w) * q2[k*4+3];
        }
        float dot = dd.x + dd.y;
        dot += __shfl_xor(dot, 1);
        dot = valid ? dot : 0.f;
        float lro = __uint_as_float(((u32)lr[o]) << 16);
        p[o] = __builtin_amdgcn_exp2f(dot + lro);
    }

    float l = 0.f;
#pragma unroll
    for (int o = 0; o < 27; ++o) l += p[o];
    float inv = 1.f / l;

    // ---- Phase 2: acc init = residual (fp32 re-read, issued here, hides under V gather) ----
    f32x2 acc[16];
    {
        const float* xv = x + ((size_t)batch * 64 + half * 32) * Sd + (s0 + vt);
#pragma unroll
        for (int i = 0; i < 16; ++i){
            acc[i].x = xv[(size_t)(2*i)     * Sd];
            acc[i].y = xv[(size_t)(2*i + 1) * Sd];
        }
    }
#pragma unroll
    for (int o = 0; o < 27; ++o){
        const int di = o / 9 - 1, dj = (o / 3) % 3 - 1, dk = o % 3 - 1;
        int doff = (di < 0 ? cdm : di > 0 ? cdp : 0)
                 + (dj < 0 ? chm : dj > 0 ? chp : 0)
                 + (dk < 0 ? cwm : dk > 0 ? cwp : 0);
        bool valid = (di < 0 ? vdm : di > 0 ? vdp : true)
                  && (dj < 0 ? vhm : dj > 0 ? vhp : true)
                  && (dk < 0 ? vwm : dk > 0 ? vwp : true);
        const uint4* p4 = reinterpret_cast<const uint4*>(KVc + (kbase + doff * 256 + 128));
        uint4 vv[4];
#pragma unroll
        for (int k = 0; k < 4; ++k) vv[k] = p4[k];
        float pv = valid ? p[o] * inv : 0.f;
        f32x2 p2 = {pv, pv};
#pragma unroll
        for (int k = 0; k < 4; ++k){
            acc[k*4+0] += unp2(vv[k].x) * p2;
            acc[k*4+1] += unp2(vv[k].y) * p2;
            acc[k*4+2] += unp2(vv[k].z) * p2;
            acc[k*4+3] += unp2(vv[k].w) * p2;
        }
    }

    // write attn-out (own half) bf16 into Lx (own wave's rows)
#pragma unroll
    for (int k = 0; k < 4; ++k){
        uint4 u;
        u.x = pk2(acc[k*4+0].x, acc[k*4+0].y);
        u.y = pk2(acc[k*4+1].x, acc[k*4+1].y);
        u.z = pk2(acc[k*4+2].x, acc[k*4+2].y);
        u.w = pk2(acc[k*4+3].x, acc[k*4+3].y);
        *reinterpret_cast<uint4*>(&Lx[vt * 72 + half * 32 + k * 8]) = u;
    }

    {   // out-projection MFMA -> fp32 stores
        short8 oa[4][2];
        f32x4  obias[4];
#pragma unroll
        for (int mt = 0; mt < 4; ++mt){
#pragma unroll
            for (int kh = 0; kh < 2; ++kh)
                oa[mt][kh] = ldfrag_w(out_w + (size_t)(mt*16 + lo) * 64 + kh*32 + hi*8);
            obias[mt] = *reinterpret_cast<const f32x4*>(out_b + mt*16 + hi*4);
        }
#pragma unroll
        for (int nt = 0; nt < 2; ++nt){
            int vl = wv * 32 + nt * 16 + lo;
            const u16* br = &Lx[vl * 72 + hi * 8];
            short8 b0 = *reinterpret_cast<const short8*>(br);
            short8 b1 = *reinterpret_cast<const short8*>(br + 32);
#pragma unroll
            for (int mt = 0; mt < 4; ++mt){
                f32x4 a4 = obias[mt];
                a4 = __builtin_amdgcn_mfma_f32_16x16x32_bf16(oa[mt][0], b0, a4, 0, 0, 0);
                a4 = __builtin_amdgcn_mfma_f32_16x16x32_bf16(oa[mt][1], b1, a4, 0, 0, 0);
                float* op = out + ((size_t)batch * 64 + mt*16 + hi*4) * Sd + (s0 + vl);
                op[0]              = a4[0];
                op[(size_t)Sd]     = a4[1];
                op[(size_t)2*Sd]   = a4[2];
                op[(size_t)3*Sd]   = a4[3];
            }
        }
    }
}

extern "C" void kernel_launch(void* const* d_in, const int* in_sizes, int n_in,
                              void* d_out, int out_size, void* d_ws, size_t ws_size,
                              hipStream_t stream) {
    const float* x       = (const float*)d_in[0];
    const float* qkv_w   = (const float*)d_in[1];
    const float* qkv_b   = (const float*)d_in[2];
    const float* out_w   = (const float*)d_in[3];
    const float* out_b   = (const float*)d_in[4];
    const float* rel_pos = (const float*)d_in[5];
    float* out = (float*)d_out;
    u16* KV = (u16*)d_ws;   // 884736 * 128 * 2B = 216 MB

    kv_mfma<<<NBLK_A, 256, 0, stream>>>(x, qkv_w, qkv_b, KV);
    attn_fused<<<NBLK_B, 256, 0, stream>>>(x, qkv_w, qkv_b, out_w, out_b,
                                           rel_pos, KV, out);
}

// Round 6
// 3474.903 us; speedup vs baseline: 1.0874x; 1.0874x over previous
//
#include <hip/hip_runtime.h>
#include <hip/hip_bf16.h>

#define Sd 442368      // D*H*W
#define HWc 9216
#define Wc 96
#define Hc 96
#define Dc 48

typedef unsigned short u16;
typedef unsigned int u32;
typedef __attribute__((ext_vector_type(8))) short short8;
typedef __attribute__((ext_vector_type(4))) float f32x4;
typedef __attribute__((ext_vector_type(2))) float f32x2;

static __device__ __forceinline__ u16 f2bf(float f){
    __hip_bfloat16 h = __float2bfloat16(f);
    return *reinterpret_cast<u16*>(&h);
}
static __device__ __forceinline__ u32 pk2(float a, float b){
    return ((u32)f2bf(b) << 16) | (u32)f2bf(a);
}
static __device__ __forceinline__ f32x2 unp2(u32 u){
    f32x2 r; r.x = __uint_as_float(u << 16); r.y = __uint_as_float(u & 0xffff0000u); return r;
}

static __device__ __forceinline__ short8 ldfrag_w(const float* p){
    float4 f0 = *reinterpret_cast<const float4*>(p);
    float4 f1 = *reinterpret_cast<const float4*>(p + 4);
    union { short8 s; u32 u[4]; } r;
    r.u[0] = pk2(f0.x, f0.y); r.u[1] = pk2(f0.z, f0.w);
    r.u[2] = pk2(f1.x, f1.y); r.u[3] = pk2(f1.z, f1.w);
    return r.s;
}

// ---------------- Pass A: K,V projection via MFMA, bf16 [vox][128] ----------------
#define NBLK_A 3456
__global__ __launch_bounds__(256, 2) void kv_mfma(
    const float* __restrict__ x, const float* __restrict__ qkv_w,
    const float* __restrict__ qkv_b, u16* __restrict__ KV)
{
    int bid = blockIdx.x;
    bid = (bid & 7) * (NBLK_A / 8) + (bid >> 3);
    int batch = bid / (NBLK_A / 2);
    int s0 = (bid - batch * (NBLK_A / 2)) * 256;
    int t = threadIdx.x, lane = t & 63, wv = t >> 6;
    int lo = lane & 15, hi = lane >> 4;
    __shared__ u16 L[256 * 72];

    const float* xb = x + (size_t)batch * 64 * Sd + s0;
    {
        u32 pk[32];
#pragma unroll
        for (int c = 0; c < 64; c += 2){
            float f0 = xb[(size_t)c * Sd + t];
            float f1 = xb[(size_t)(c + 1) * Sd + t];
            pk[c >> 1] = pk2(f0, f1);
        }
#pragma unroll
        for (int k = 0; k < 8; ++k){
            uint4 u; u.x = pk[k*4+0]; u.y = pk[k*4+1]; u.z = pk[k*4+2]; u.w = pk[k*4+3];
            *reinterpret_cast<uint4*>(&L[t * 72 + k * 8]) = u;
        }
    }
    // wave-local staging: thread t writes row t; wave reads rows [wv*64, wv*64+64)

    short8 af[8][2];
    f32x4  bias[8];
#pragma unroll
    for (int mt = 0; mt < 8; ++mt){
#pragma unroll
        for (int kh = 0; kh < 2; ++kh)
            af[mt][kh] = ldfrag_w(qkv_w + (size_t)(64 + mt*16 + lo) * 64 + kh*32 + hi*8);
        bias[mt] = *reinterpret_cast<const f32x4*>(qkv_b + 64 + mt*16 + hi*4);
    }

#pragma unroll
    for (int nt = 0; nt < 4; ++nt){
        int vl = wv * 64 + nt * 16 + lo;
        const u16* br = &L[vl * 72 + hi * 8];
        short8 b0 = *reinterpret_cast<const short8*>(br);
        short8 b1 = *reinterpret_cast<const short8*>(br + 32);
        u16* kvrow = KV + (size_t)(batch * Sd + s0 + vl) * 128 + hi * 4;
#pragma unroll
        for (int mt = 0; mt < 8; ++mt){
            f32x4 acc = bias[mt];
            acc = __builtin_amdgcn_mfma_f32_16x16x32_bf16(af[mt][0], b0, acc, 0, 0, 0);
            acc = __builtin_amdgcn_mfma_f32_16x16x32_bf16(af[mt][1], b1, acc, 0, 0, 0);
            uint2 st; st.x = pk2(acc[0], acc[1]); st.y = pk2(acc[2], acc[3]);
            *reinterpret_cast<uint2*>(kvrow + mt * 16) = st;
        }
    }
}

// ---------------- Pass B: two-phase no-max softmax attention, 2 threads/voxel ----------------
#define NBLK_B 6912
#define SCLOG 0.18033688011112042f   // 0.125 * log2(e)

__global__ __launch_bounds__(256, 4) void attn_fused(
    const float* __restrict__ x, const float* __restrict__ qkv_w,
    const float* __restrict__ qkv_b, const float* __restrict__ out_w,
    const float* __restrict__ out_b, const float* __restrict__ rel_pos,
    const u16* __restrict__ KV, float* __restrict__ out)
{
    int bid = blockIdx.x;
    bid = (bid & 7) * (NBLK_B / 8) + (bid >> 3);
    int batch = bid / (NBLK_B / 2);
    int s0 = (bid - batch * (NBLK_B / 2)) * 128;
    int t = threadIdx.x, lane = t & 63, wv = t >> 6;
    int lo = lane & 15, hi = lane >> 4;
    int vt = t >> 1, half = t & 1;

    __shared__ u16 Lx[128 * 72];     // x bf16 -> Q bf16 (in place) -> attn-out bf16
    __shared__ u16 Lr16[128 * 28];   // rel-logits bf16, pre-scaled by SCLOG

    const float* xb = x + (size_t)batch * 64 * Sd + s0;
    {   // stage own 32 channels of voxel vt (wave-local rows)
        u32 pk[16];
#pragma unroll
        for (int c2 = 0; c2 < 32; c2 += 2){
            float f0 = xb[(size_t)(half*32 + c2) * Sd + vt];
            float f1 = xb[(size_t)(half*32 + c2 + 1) * Sd + vt];
            pk[c2 >> 1] = pk2(f0, f1);
        }
#pragma unroll
        for (int k = 0; k < 4; ++k){
            uint4 u; u.x = pk[k*4+0]; u.y = pk[k*4+1]; u.z = pk[k*4+2]; u.w = pk[k*4+3];
            *reinterpret_cast<uint4*>(&Lx[vt * 72 + half * 32 + k * 8]) = u;
        }
    }

    {   // Q-projection MFMA; overwrite own wave's rows of Lx with Q bf16
        short8 qa[4][2];
        f32x4  qbias[4];
#pragma unroll
        for (int mt = 0; mt < 4; ++mt){
#pragma unroll
            for (int kh = 0; kh < 2; ++kh)
                qa[mt][kh] = ldfrag_w(qkv_w + (size_t)(mt*16 + lo) * 64 + kh*32 + hi*8);
            qbias[mt] = *reinterpret_cast<const f32x4*>(qkv_b + mt*16 + hi*4);
        }
#pragma unroll
        for (int nt = 0; nt < 2; ++nt){
            int vl = wv * 32 + nt * 16 + lo;
            const u16* br = &Lx[vl * 72 + hi * 8];
            short8 b0 = *reinterpret_cast<const short8*>(br);
            short8 b1 = *reinterpret_cast<const short8*>(br + 32);
#pragma unroll
            for (int mt = 0; mt < 4; ++mt){
                f32x4 acc = qbias[mt];
                acc = __builtin_amdgcn_mfma_f32_16x16x32_bf16(qa[mt][0], b0, acc, 0, 0, 0);
                acc = __builtin_amdgcn_mfma_f32_16x16x32_bf16(qa[mt][1], b1, acc, 0, 0, 0);
                uint2 st; st.x = pk2(acc[0], acc[1]); st.y = pk2(acc[2], acc[3]);
                *reinterpret_cast<uint2*>(&Lx[vl * 72 + mt * 16 + hi * 4]) = st;
            }
        }
    }

    {   // rel-logits MFMA: R(27x64 pad 32) x Q -> Lr16 bf16 (scaled by SCLOG)
        short8 ra[2][2];
#pragma unroll
        for (int mt = 0; mt < 2; ++mt){
            int o = mt * 16 + lo;
#pragma unroll
            for (int kh = 0; kh < 2; ++kh){
                float f[8];
#pragma unroll
                for (int j = 0; j < 8; ++j){
                    int k = kh * 32 + hi * 8 + j;
                    f[j] = (o < 27) ? rel_pos[k * 27 + o] : 0.f;
                }
                union { short8 s; u32 u[4]; } r;
                r.u[0] = pk2(f[0], f[1]); r.u[1] = pk2(f[2], f[3]);
                r.u[2] = pk2(f[4], f[5]); r.u[3] = pk2(f[6], f[7]);
                ra[mt][kh] = r.s;
            }
        }
        u32* Lr32 = reinterpret_cast<u32*>(Lr16);
#pragma unroll
        for (int nt = 0; nt < 2; ++nt){
            int vl = wv * 32 + nt * 16 + lo;
            const u16* br = &Lx[vl * 72 + hi * 8];
            short8 b0 = *reinterpret_cast<const short8*>(br);
            short8 b1 = *reinterpret_cast<const short8*>(br + 32);
            f32x4 a0 = {0.f, 0.f, 0.f, 0.f};
            f32x4 a1 = {0.f, 0.f, 0.f, 0.f};
            a0 = __builtin_amdgcn_mfma_f32_16x16x32_bf16(ra[0][0], b0, a0, 0, 0, 0);
            a0 = __builtin_amdgcn_mfma_f32_16x16x32_bf16(ra[0][1], b1, a0, 0, 0, 0);
            a1 = __builtin_amdgcn_mfma_f32_16x16x32_bf16(ra[1][0], b0, a1, 0, 0, 0);
            a1 = __builtin_amdgcn_mfma_f32_16x16x32_bf16(ra[1][1], b1, a1, 0, 0, 0);
            // rows hi*4+{0..3} at col vl, packed pairs -> dwords
            Lr32[vl * 14 + hi * 2 + 0] = pk2(a0[0] * SCLOG, a0[1] * SCLOG);
            Lr32[vl * 14 + hi * 2 + 1] = pk2(a0[2] * SCLOG, a0[3] * SCLOG);
            if (hi < 3){   // rows 16+hi*4+{0..3} (row 27 slot is padding, never read)
                Lr32[vl * 14 + 8 + hi * 2 + 0] = pk2(a1[0] * SCLOG, a1[1] * SCLOG);
                Lr32[vl * 14 + 8 + hi * 2 + 1] = pk2(a1[2] * SCLOG, a1[3] * SCLOG);
            }
        }
    }

    // per-thread: own half of Q, pre-scaled, as f32x2 pairs
    f32x2 q2[16];
#pragma unroll
    for (int k = 0; k < 4; ++k){
        uint4 q4 = *reinterpret_cast<const uint4*>(&Lx[vt * 72 + half * 32 + k * 8]);
        q2[k*4+0] = unp2(q4.x) * SCLOG;
        q2[k*4+1] = unp2(q4.y) * SCLOG;
        q2[k*4+2] = unp2(q4.z) * SCLOG;
        q2[k*4+3] = unp2(q4.w) * SCLOG;
    }

    int s = s0 + vt;
    int d = s / HWc; int r = s - d * HWc; int h3 = r / Wc; int w3 = r - h3 * Wc;

    int cdm = (d  > 0)      ? -HWc : 0;
    int cdp = (d  < Dc - 1) ?  HWc : 0;
    int chm = (h3 > 0)      ? -Wc  : 0;
    int chp = (h3 < Hc - 1) ?  Wc  : 0;
    int cwm = (w3 > 0)      ? -1   : 0;
    int cwp = (w3 < Wc - 1) ?  1   : 0;
    bool vdm = d  > 0, vdp = d  < Dc - 1;
    bool vhm = h3 > 0, vhp = h3 < Hc - 1;
    bool vwm = w3 > 0, vwp = w3 < Wc - 1;

    const char* KVc = reinterpret_cast<const char*>(KV);
    int kbase = (batch * Sd + s) * 256 + half * 64;
    const u16* lr = &Lr16[vt * 28];

    // ---- Phase 1: 27 independent K-dots -> p[o] (no max subtraction; logits bounded) ----
    float p[27];
#pragma unroll
    for (int o = 0; o < 27; ++o){
        const int di = o / 9 - 1, dj = (o / 3) % 3 - 1, dk = o % 3 - 1;
        int doff = (di < 0 ? cdm : di > 0 ? cdp : 0)
                 + (dj < 0 ? chm : dj > 0 ? chp : 0)
                 + (dk < 0 ? cwm : dk > 0 ? cwp : 0);
        bool valid = (di < 0 ? vdm : di > 0 ? vdp : true)
                  && (dj < 0 ? vhm : dj > 0 ? vhp : true)
                  && (dk < 0 ? vwm : dk > 0 ? vwp : true);
        const uint4* p4 = reinterpret_cast<const uint4*>(KVc + (kbase + doff * 256));
        uint4 kk[4];
#pragma unroll
        for (int k = 0; k < 4; ++k) kk[k] = p4[k];
        f32x2 dd = {0.f, 0.f};
#pragma unroll
        for (int k = 0; k < 4; ++k){
            dd += unp2(kk[k].x) * q2[k*4+0];
            dd += unp2(kk[k].y) * q2[k*4+1];
            dd += unp2(kk[k].z) * q2[k*4+2];
            dd += unp2(kk[k].w) * q2[k*4+3];
        }
        float dot = dd.x + dd.y;
        dot += __shfl_xor(dot, 1);
        dot = valid ? dot : 0.f;
        float lro = __uint_as_float(((u32)lr[o]) << 16);
        p[o] = __builtin_amdgcn_exp2f(dot + lro);
    }

    float l = 0.f;
#pragma unroll
    for (int o = 0; o < 27; ++o) l += p[o];
    float inv = 1.f / l;

    // ---- Phase 2: acc init = residual (fp32 re-read, issued here, hides under V gather) ----
    f32x2 acc[16];
    {
        const float* xv = x + ((size_t)batch * 64 + half * 32) * Sd + (s0 + vt);
#pragma unroll
        for (int i = 0; i < 16; ++i){
            acc[i].x = xv[(size_t)(2*i)     * Sd];
            acc[i].y = xv[(size_t)(2*i + 1) * Sd];
        }
    }
#pragma unroll
    for (int o = 0; o < 27; ++o){
        const int di = o / 9 - 1, dj = (o / 3) % 3 - 1, dk = o % 3 - 1;
        int doff = (di < 0 ? cdm : di > 0 ? cdp : 0)
                 + (dj < 0 ? chm : dj > 0 ? chp : 0)
                 + (dk < 0 ? cwm : dk > 0 ? cwp : 0);
        bool valid = (di < 0 ? vdm : di > 0 ? vdp : true)
                  && (dj < 0 ? vhm : dj > 0 ? vhp : true)
                  && (dk < 0 ? vwm : dk > 0 ? vwp : true);
        const uint4* p4 = reinterpret_cast<const uint4*>(KVc + (kbase + doff * 256 + 128));
        uint4 vv[4];
#pragma unroll
        for (int k = 0; k < 4; ++k) vv[k] = p4[k];
        float pv = valid ? p[o] * inv : 0.f;
        f32x2 p2 = {pv, pv};
#pragma unroll
        for (int k = 0; k < 4; ++k){
            acc[k*4+0] += unp2(vv[k].x) * p2;
            acc[k*4+1] += unp2(vv[k].y) * p2;
            acc[k*4+2] += unp2(vv[k].z) * p2;
            acc[k*4+3] += unp2(vv[k].w) * p2;
        }
    }

    // write attn-out (own half) bf16 into Lx (own wave's rows)
#pragma unroll
    for (int k = 0; k < 4; ++k){
        uint4 u;
        u.x = pk2(acc[k*4+0].x, acc[k*4+0].y);
        u.y = pk2(acc[k*4+1].x, acc[k*4+1].y);
        u.z = pk2(acc[k*4+2].x, acc[k*4+2].y);
        u.w = pk2(acc[k*4+3].x, acc[k*4+3].y);
        *reinterpret_cast<uint4*>(&Lx[vt * 72 + half * 32 + k * 8]) = u;
    }

    {   // out-projection MFMA -> fp32 stores
        short8 oa[4][2];
        f32x4  obias[4];
#pragma unroll
        for (int mt = 0; mt < 4; ++mt){
#pragma unroll
            for (int kh = 0; kh < 2; ++kh)
                oa[mt][kh] = ldfrag_w(out_w + (size_t)(mt*16 + lo) * 64 + kh*32 + hi*8);
            obias[mt] = *reinterpret_cast<const f32x4*>(out_b + mt*16 + hi*4);
        }
#pragma unroll
        for (int nt = 0; nt < 2; ++nt){
            int vl = wv * 32 + nt * 16 + lo;
            const u16* br = &Lx[vl * 72 + hi * 8];
            short8 b0 = *reinterpret_cast<const short8*>(br);
            short8 b1 = *reinterpret_cast<const short8*>(br + 32);
#pragma unroll
            for (int mt = 0; mt < 4; ++mt){
                f32x4 a4 = obias[mt];
                a4 = __builtin_amdgcn_mfma_f32_16x16x32_bf16(oa[mt][0], b0, a4, 0, 0, 0);
                a4 = __builtin_amdgcn_mfma_f32_16x16x32_bf16(oa[mt][1], b1, a4, 0, 0, 0);
                float* op = out + ((size_t)batch * 64 + mt*16 + hi*4) * Sd + (s0 + vl);
                op[0]              = a4[0];
                op[(size_t)Sd]     = a4[1];
                op[(size_t)2*Sd]   = a4[2];
                op[(size_t)3*Sd]   = a4[3];
            }
        }
    }
}

extern "C" void kernel_launch(void* const* d_in, const int* in_sizes, int n_in,
                              void* d_out, int out_size, void* d_ws, size_t ws_size,
                              hipStream_t stream) {
    const float* x       = (const float*)d_in[0];
    const float* qkv_w   = (const float*)d_in[1];
    const float* qkv_b   = (const float*)d_in[2];
    const float* out_w   = (const float*)d_in[3];
    const float* out_b   = (const float*)d_in[4];
    const float* rel_pos = (const float*)d_in[5];
    float* out = (float*)d_out;
    u16* KV = (u16*)d_ws;   // 884736 * 128 * 2B = 216 MB

    kv_mfma<<<NBLK_A, 256, 0, stream>>>(x, qkv_w, qkv_b, KV);
    attn_fused<<<NBLK_B, 256, 0, stream>>>(x, qkv_w, qkv_b, out_w, out_b,
                                           rel_pos, KV, out);
}

// Round 7
// 3430.786 us; speedup vs baseline: 1.1014x; 1.0129x over previous
//
#include <hip/hip_runtime.h>
#include <hip/hip_bf16.h>

#define Sd 442368      // D*H*W
#define HWc 9216
#define Wc 96
#define Hc 96
#define Dc 48

typedef unsigned short u16;
typedef unsigned int u32;
typedef __attribute__((ext_vector_type(8))) short short8;
typedef __attribute__((ext_vector_type(4))) float f32x4;
typedef __attribute__((ext_vector_type(2))) float f32x2;

static __device__ __forceinline__ u16 f2bf(float f){
    __hip_bfloat16 h = __float2bfloat16(f);
    return *reinterpret_cast<u16*>(&h);
}
static __device__ __forceinline__ u32 pk2(float a, float b){
    return ((u32)f2bf(b) << 16) | (u32)f2bf(a);
}
static __device__ __forceinline__ f32x2 unp2(u32 u){
    f32x2 r; r.x = __uint_as_float(u << 16); r.y = __uint_as_float(u & 0xffff0000u); return r;
}

static __device__ __forceinline__ short8 ldfrag_w(const float* p){
    float4 f0 = *reinterpret_cast<const float4*>(p);
    float4 f1 = *reinterpret_cast<const float4*>(p + 4);
    union { short8 s; u32 u[4]; } r;
    r.u[0] = pk2(f0.x, f0.y); r.u[1] = pk2(f0.z, f0.w);
    r.u[2] = pk2(f1.x, f1.y); r.u[3] = pk2(f1.z, f1.w);
    return r.s;
}

// ---------------- Pass A: K,V projection via MFMA, bf16 [vox][128] ----------------
#define NBLK_A 3456
__global__ __launch_bounds__(256, 2) void kv_mfma(
    const float* __restrict__ x, const float* __restrict__ qkv_w,
    const float* __restrict__ qkv_b, u16* __restrict__ KV)
{
    int bid = blockIdx.x;
    bid = (bid & 7) * (NBLK_A / 8) + (bid >> 3);
    int batch = bid / (NBLK_A / 2);
    int s0 = (bid - batch * (NBLK_A / 2)) * 256;
    int t = threadIdx.x, lane = t & 63, wv = t >> 6;
    int lo = lane & 15, hi = lane >> 4;
    __shared__ u16 L[256 * 72];

    const float* xb = x + (size_t)batch * 64 * Sd + s0;
    {
        u32 pk[32];
#pragma unroll
        for (int c = 0; c < 64; c += 2){
            float f0 = xb[(size_t)c * Sd + t];
            float f1 = xb[(size_t)(c + 1) * Sd + t];
            pk[c >> 1] = pk2(f0, f1);
        }
#pragma unroll
        for (int k = 0; k < 8; ++k){
            uint4 u; u.x = pk[k*4+0]; u.y = pk[k*4+1]; u.z = pk[k*4+2]; u.w = pk[k*4+3];
            *reinterpret_cast<uint4*>(&L[t * 72 + k * 8]) = u;
        }
    }
    // wave-local staging: thread t writes row t; wave reads rows [wv*64, wv*64+64)

    short8 af[8][2];
    f32x4  bias[8];
#pragma unroll
    for (int mt = 0; mt < 8; ++mt){
#pragma unroll
        for (int kh = 0; kh < 2; ++kh)
            af[mt][kh] = ldfrag_w(qkv_w + (size_t)(64 + mt*16 + lo) * 64 + kh*32 + hi*8);
        bias[mt] = *reinterpret_cast<const f32x4*>(qkv_b + 64 + mt*16 + hi*4);
    }

#pragma unroll
    for (int nt = 0; nt < 4; ++nt){
        int vl = wv * 64 + nt * 16 + lo;
        const u16* br = &L[vl * 72 + hi * 8];
        short8 b0 = *reinterpret_cast<const short8*>(br);
        short8 b1 = *reinterpret_cast<const short8*>(br + 32);
        u16* kvrow = KV + (size_t)(batch * Sd + s0 + vl) * 128 + hi * 4;
#pragma unroll
        for (int mt = 0; mt < 8; ++mt){
            f32x4 acc = bias[mt];
            acc = __builtin_amdgcn_mfma_f32_16x16x32_bf16(af[mt][0], b0, acc, 0, 0, 0);
            acc = __builtin_amdgcn_mfma_f32_16x16x32_bf16(af[mt][1], b1, acc, 0, 0, 0);
            uint2 st; st.x = pk2(acc[0], acc[1]); st.y = pk2(acc[2], acc[3]);
            *reinterpret_cast<uint2*>(kvrow + mt * 16) = st;
        }
    }
}

// ---------------- Pass B: two-phase softmax attention, p[] in LDS ----------------
#define NBLK_B 6912
#define SCLOG 0.18033688011112042f   // 0.125 * log2(e)

__global__ __launch_bounds__(256, 4) void attn_fused(
    const float* __restrict__ x, const float* __restrict__ qkv_w,
    const float* __restrict__ qkv_b, const float* __restrict__ out_w,
    const float* __restrict__ out_b, const float* __restrict__ rel_pos,
    const u16* __restrict__ KV, float* __restrict__ out)
{
    int bid = blockIdx.x;
    bid = (bid & 7) * (NBLK_B / 8) + (bid >> 3);
    int batch = bid / (NBLK_B / 2);
    int s0 = (bid - batch * (NBLK_B / 2)) * 128;
    int t = threadIdx.x, lane = t & 63, wv = t >> 6;
    int lo = lane & 15, hi = lane >> 4;
    int vt = t >> 1, half = t & 1;

    __shared__ u16  Lx[128 * 72];    // x bf16 -> Q bf16 (in place) -> attn-out bf16
    __shared__ float Lp[128 * 29];   // rel-logits fp32 (scaled) -> p[] (stride 29: conflict-free)

    const float* xb = x + (size_t)batch * 64 * Sd + s0;
    {   // stage own 32 channels of voxel vt (wave-local rows)
        u32 pk[16];
#pragma unroll
        for (int c2 = 0; c2 < 32; c2 += 2){
            float f0 = xb[(size_t)(half*32 + c2) * Sd + vt];
            float f1 = xb[(size_t)(half*32 + c2 + 1) * Sd + vt];
            pk[c2 >> 1] = pk2(f0, f1);
        }
#pragma unroll
        for (int k = 0; k < 4; ++k){
            uint4 u; u.x = pk[k*4+0]; u.y = pk[k*4+1]; u.z = pk[k*4+2]; u.w = pk[k*4+3];
            *reinterpret_cast<uint4*>(&Lx[vt * 72 + half * 32 + k * 8]) = u;
        }
    }

    {   // Q-projection MFMA; overwrite own wave's rows of Lx with Q bf16
        short8 qa[4][2];
        f32x4  qbias[4];
#pragma unroll
        for (int mt = 0; mt < 4; ++mt){
#pragma unroll
            for (int kh = 0; kh < 2; ++kh)
                qa[mt][kh] = ldfrag_w(qkv_w + (size_t)(mt*16 + lo) * 64 + kh*32 + hi*8);
            qbias[mt] = *reinterpret_cast<const f32x4*>(qkv_b + mt*16 + hi*4);
        }
#pragma unroll
        for (int nt = 0; nt < 2; ++nt){
            int vl = wv * 32 + nt * 16 + lo;
            const u16* br = &Lx[vl * 72 + hi * 8];
            short8 b0 = *reinterpret_cast<const short8*>(br);
            short8 b1 = *reinterpret_cast<const short8*>(br + 32);
#pragma unroll
            for (int mt = 0; mt < 4; ++mt){
                f32x4 acc = qbias[mt];
                acc = __builtin_amdgcn_mfma_f32_16x16x32_bf16(qa[mt][0], b0, acc, 0, 0, 0);
                acc = __builtin_amdgcn_mfma_f32_16x16x32_bf16(qa[mt][1], b1, acc, 0, 0, 0);
                uint2 st; st.x = pk2(acc[0], acc[1]); st.y = pk2(acc[2], acc[3]);
                *reinterpret_cast<uint2*>(&Lx[vl * 72 + mt * 16 + hi * 4]) = st;
            }
        }
    }

    {   // rel-logits MFMA: R(27x64 pad 32) x Q -> Lp fp32 (scaled by SCLOG)
        short8 ra[2][2];
#pragma unroll
        for (int mt = 0; mt < 2; ++mt){
            int o = mt * 16 + lo;
#pragma unroll
            for (int kh = 0; kh < 2; ++kh){
                float f[8];
#pragma unroll
                for (int j = 0; j < 8; ++j){
                    int k = kh * 32 + hi * 8 + j;
                    f[j] = (o < 27) ? rel_pos[k * 27 + o] : 0.f;
                }
                union { short8 s; u32 u[4]; } r;
                r.u[0] = pk2(f[0], f[1]); r.u[1] = pk2(f[2], f[3]);
                r.u[2] = pk2(f[4], f[5]); r.u[3] = pk2(f[6], f[7]);
                ra[mt][kh] = r.s;
            }
        }
#pragma unroll
        for (int nt = 0; nt < 2; ++nt){
            int vl = wv * 32 + nt * 16 + lo;
            const u16* br = &Lx[vl * 72 + hi * 8];
            short8 b0 = *reinterpret_cast<const short8*>(br);
            short8 b1 = *reinterpret_cast<const short8*>(br + 32);
            f32x4 a0 = {0.f, 0.f, 0.f, 0.f};
            f32x4 a1 = {0.f, 0.f, 0.f, 0.f};
            a0 = __builtin_amdgcn_mfma_f32_16x16x32_bf16(ra[0][0], b0, a0, 0, 0, 0);
            a0 = __builtin_amdgcn_mfma_f32_16x16x32_bf16(ra[0][1], b1, a0, 0, 0, 0);
            a1 = __builtin_amdgcn_mfma_f32_16x16x32_bf16(ra[1][0], b0, a1, 0, 0, 0);
            a1 = __builtin_amdgcn_mfma_f32_16x16x32_bf16(ra[1][1], b1, a1, 0, 0, 0);
            // rows hi*4+{0..3} at col vl
#pragma unroll
            for (int j = 0; j < 4; ++j)
                Lp[vl * 29 + hi * 4 + j] = a0[j] * SCLOG;
            if (hi < 3){   // rows 16..27 (row 27 is padding, never read)
#pragma unroll
                for (int j = 0; j < 4; ++j)
                    Lp[vl * 29 + 16 + hi * 4 + j] = a1[j] * SCLOG;
            }
        }
    }

    // per-thread: own half of Q, pre-scaled, as f32x2 pairs
    f32x2 q2[16];
#pragma unroll
    for (int k = 0; k < 4; ++k){
        uint4 q4 = *reinterpret_cast<const uint4*>(&Lx[vt * 72 + half * 32 + k * 8]);
        q2[k*4+0] = unp2(q4.x) * SCLOG;
        q2[k*4+1] = unp2(q4.y) * SCLOG;
        q2[k*4+2] = unp2(q4.z) * SCLOG;
        q2[k*4+3] = unp2(q4.w) * SCLOG;
    }

    int s = s0 + vt;
    int d = s / HWc; int r = s - d * HWc; int h3 = r / Wc; int w3 = r - h3 * Wc;

    int cdm = (d  > 0)      ? -HWc : 0;
    int cdp = (d  < Dc - 1) ?  HWc : 0;
    int chm = (h3 > 0)      ? -Wc  : 0;
    int chp = (h3 < Hc - 1) ?  Wc  : 0;
    int cwm = (w3 > 0)      ? -1   : 0;
    int cwp = (w3 < Wc - 1) ?  1   : 0;
    bool vdm = d  > 0, vdp = d  < Dc - 1;
    bool vhm = h3 > 0, vhp = h3 < Hc - 1;
    bool vwm = w3 > 0, vwp = w3 < Wc - 1;

    const char* KVc = reinterpret_cast<const char*>(KV);
    int kbase = (batch * Sd + s) * 256 + half * 64;
    float* lp = &Lp[vt * 29];

    // ---- Phase 1: 27 independent K-dots -> p written back into Lp (no live p[] regs) ----
    float l = 0.f;
#pragma unroll
    for (int o = 0; o < 27; ++o){
        const int di = o / 9 - 1, dj = (o / 3) % 3 - 1, dk = o % 3 - 1;
        int doff = (di < 0 ? cdm : di > 0 ? cdp : 0)
                 + (dj < 0 ? chm : dj > 0 ? chp : 0)
                 + (dk < 0 ? cwm : dk > 0 ? cwp : 0);
        bool valid = (di < 0 ? vdm : di > 0 ? vdp : true)
                  && (dj < 0 ? vhm : dj > 0 ? vhp : true)
                  && (dk < 0 ? vwm : dk > 0 ? vwp : true);
        const uint4* p4 = reinterpret_cast<const uint4*>(KVc + (kbase + doff * 256));
        uint4 kk[4];
#pragma unroll
        for (int k = 0; k < 4; ++k) kk[k] = p4[k];
        f32x2 dd = {0.f, 0.f};
#pragma unroll
        for (int k = 0; k < 4; ++k){
            dd += unp2(kk[k].x) * q2[k*4+0];
            dd += unp2(kk[k].y) * q2[k*4+1];
            dd += unp2(kk[k].z) * q2[k*4+2];
            dd += unp2(kk[k].w) * q2[k*4+3];
        }
        float dot = dd.x + dd.y;
        dot += __shfl_xor(dot, 1);
        dot = valid ? dot : 0.f;
        float p = __builtin_amdgcn_exp2f(dot + lp[o]);
        l += p;
        lp[o] = p;    // both lanes of pair write identical value (wave-local, in-order)
    }
    float inv = 1.f / l;

    // ---- Phase 2: acc init = residual (fp32 re-read, hides under V gather) ----
    f32x2 acc[16];
    {
        const float* xv = x + ((size_t)batch * 64 + half * 32) * Sd + (s0 + vt);
#pragma unroll
        for (int i = 0; i < 16; ++i){
            acc[i].x = xv[(size_t)(2*i)     * Sd];
            acc[i].y = xv[(size_t)(2*i + 1) * Sd];
        }
    }
#pragma unroll
    for (int o = 0; o < 27; ++o){
        const int di = o / 9 - 1, dj = (o / 3) % 3 - 1, dk = o % 3 - 1;
        int doff = (di < 0 ? cdm : di > 0 ? cdp : 0)
                 + (dj < 0 ? chm : dj > 0 ? chp : 0)
                 + (dk < 0 ? cwm : dk > 0 ? cwp : 0);
        bool valid = (di < 0 ? vdm : di > 0 ? vdp : true)
                  && (dj < 0 ? vhm : dj > 0 ? vhp : true)
                  && (dk < 0 ? vwm : dk > 0 ? vwp : true);
        const uint4* p4 = reinterpret_cast<const uint4*>(KVc + (kbase + doff * 256 + 128));
        uint4 vv[4];
#pragma unroll
        for (int k = 0; k < 4; ++k) vv[k] = p4[k];
        float pv = valid ? lp[o] * inv : 0.f;
        f32x2 p2 = {pv, pv};
#pragma unroll
        for (int k = 0; k < 4; ++k){
            acc[k*4+0] += unp2(vv[k].x) * p2;
            acc[k*4+1] += unp2(vv[k].y) * p2;
            acc[k*4+2] += unp2(vv[k].z) * p2;
            acc[k*4+3] += unp2(vv[k].w) * p2;
        }
    }

    // write attn-out (own half) bf16 into Lx (own wave's rows)
#pragma unroll
    for (int k = 0; k < 4; ++k){
        uint4 u;
        u.x = pk2(acc[k*4+0].x, acc[k*4+0].y);
        u.y = pk2(acc[k*4+1].x, acc[k*4+1].y);
        u.z = pk2(acc[k*4+2].x, acc[k*4+2].y);
        u.w = pk2(acc[k*4+3].x, acc[k*4+3].y);
        *reinterpret_cast<uint4*>(&Lx[vt * 72 + half * 32 + k * 8]) = u;
    }

    {   // out-projection MFMA -> fp32 stores
        short8 oa[4][2];
        f32x4  obias[4];
#pragma unroll
        for (int mt = 0; mt < 4; ++mt){
#pragma unroll
            for (int kh = 0; kh < 2; ++kh)
                oa[mt][kh] = ldfrag_w(out_w + (size_t)(mt*16 + lo) * 64 + kh*32 + hi*8);
            obias[mt] = *reinterpret_cast<const f32x4*>(out_b + mt*16 + hi*4);
        }
#pragma unroll
        for (int nt = 0; nt < 2; ++nt){
            int vl = wv * 32 + nt * 16 + lo;
            const u16* br = &Lx[vl * 72 + hi * 8];
            short8 b0 = *reinterpret_cast<const short8*>(br);
            short8 b1 = *reinterpret_cast<const short8*>(br + 32);
#pragma unroll
            for (int mt = 0; mt < 4; ++mt){
                f32x4 a4 = obias[mt];
                a4 = __builtin_amdgcn_mfma_f32_16x16x32_bf16(oa[mt][0], b0, a4, 0, 0, 0);
                a4 = __builtin_amdgcn_mfma_f32_16x16x32_bf16(oa[mt][1], b1, a4, 0, 0, 0);
                float* op = out + ((size_t)batch * 64 + mt*16 + hi*4) * Sd + (s0 + vl);
                op[0]              = a4[0];
                op[(size_t)Sd]     = a4[1];
                op[(size_t)2*Sd]   = a4[2];
                op[(size_t)3*Sd]   = a4[3];
            }
        }
    }
}

extern "C" void kernel_launch(void* const* d_in, const int* in_sizes, int n_in,
                              void* d_out, int out_size, void* d_ws, size_t ws_size,
                              hipStream_t stream) {
    const float* x       = (const float*)d_in[0];
    const float* qkv_w   = (const float*)d_in[1];
    const float* qkv_b   = (const float*)d_in[2];
    const float* out_w   = (const float*)d_in[3];
    const float* out_b   = (const float*)d_in[4];
    const float* rel_pos = (const float*)d_in[5];
    float* out = (float*)d_out;
    u16* KV = (u16*)d_ws;   // 884736 * 128 * 2B = 216 MB

    kv_mfma<<<NBLK_A, 256, 0, stream>>>(x, qkv_w, qkv_b, KV);
    attn_fused<<<NBLK_B, 256, 0, stream>>>(x, qkv_w, qkv_b, out_w, out_b,
                                           rel_pos, KV, out);
}

// Round 8
// 894.795 us; speedup vs baseline: 4.2228x; 3.8342x over previous
//
#include <hip/hip_runtime.h>
#include <hip/hip_bf16.h>

#define Sd 442368      // D*H*W
#define HWc 9216
#define Wc 96
#define Hc 96
#define Dc 48

typedef unsigned short u16;
typedef unsigned int u32;
typedef __attribute__((ext_vector_type(8))) short short8;
typedef __attribute__((ext_vector_type(4))) float f32x4;

static __device__ __forceinline__ u16 f2bf(float f){
    __hip_bfloat16 h = __float2bfloat16(f);
    return *reinterpret_cast<u16*>(&h);
}
static __device__ __forceinline__ u32 pk2(float a, float b){
    return ((u32)f2bf(b) << 16) | (u32)f2bf(a);
}
static __device__ __forceinline__ float bflo(u32 u){ return __uint_as_float(u << 16); }
static __device__ __forceinline__ float bfhi(u32 u){ return __uint_as_float(u & 0xffff0000u); }

static __device__ __forceinline__ short8 ldfrag_w(const float* p){
    float4 f0 = *reinterpret_cast<const float4*>(p);
    float4 f1 = *reinterpret_cast<const float4*>(p + 4);
    union { short8 s; u32 u[4]; } r;
    r.u[0] = pk2(f0.x, f0.y); r.u[1] = pk2(f0.z, f0.w);
    r.u[2] = pk2(f1.x, f1.y); r.u[3] = pk2(f1.z, f1.w);
    return r.s;
}

// ---------------- Pass A: K,V projection via MFMA, bf16 [vox][128] ----------------
#define NBLK_A 3456
__global__ __launch_bounds__(256, 2) void kv_mfma(
    const float* __restrict__ x, const float* __restrict__ qkv_w,
    const float* __restrict__ qkv_b, u16* __restrict__ KV)
{
    int bid = blockIdx.x;
    bid = (bid & 7) * (NBLK_A / 8) + (bid >> 3);
    int batch = bid / (NBLK_A / 2);
    int s0 = (bid - batch * (NBLK_A / 2)) * 256;
    int t = threadIdx.x, lane = t & 63, wv = t >> 6;
    int lo = lane & 15, hi = lane >> 4;
    __shared__ u16 L[256 * 72];

    const float* xb = x + (size_t)batch * 64 * Sd + s0;
    {
        u32 pk[32];
#pragma unroll
        for (int c = 0; c < 64; c += 2){
            float f0 = xb[(size_t)c * Sd + t];
            float f1 = xb[(size_t)(c + 1) * Sd + t];
            pk[c >> 1] = pk2(f0, f1);
        }
#pragma unroll
        for (int k = 0; k < 8; ++k){
            uint4 u; u.x = pk[k*4+0]; u.y = pk[k*4+1]; u.z = pk[k*4+2]; u.w = pk[k*4+3];
            *reinterpret_cast<uint4*>(&L[t * 72 + k * 8]) = u;
        }
    }
    // wave-local staging: thread t writes row t; wave reads rows [wv*64, wv*64+64)

    short8 af[8][2];
    f32x4  bias[8];
#pragma unroll
    for (int mt = 0; mt < 8; ++mt){
#pragma unroll
        for (int kh = 0; kh < 2; ++kh)
            af[mt][kh] = ldfrag_w(qkv_w + (size_t)(64 + mt*16 + lo) * 64 + kh*32 + hi*8);
        bias[mt] = *reinterpret_cast<const f32x4*>(qkv_b + 64 + mt*16 + hi*4);
    }

#pragma unroll
    for (int nt = 0; nt < 4; ++nt){
        int vl = wv * 64 + nt * 16 + lo;
        const u16* br = &L[vl * 72 + hi * 8];
        short8 b0 = *reinterpret_cast<const short8*>(br);
        short8 b1 = *reinterpret_cast<const short8*>(br + 32);
        u16* kvrow = KV + (size_t)(batch * Sd + s0 + vl) * 128 + hi * 4;
#pragma unroll
        for (int mt = 0; mt < 8; ++mt){
            f32x4 acc = bias[mt];
            acc = __builtin_amdgcn_mfma_f32_16x16x32_bf16(af[mt][0], b0, acc, 0, 0, 0);
            acc = __builtin_amdgcn_mfma_f32_16x16x32_bf16(af[mt][1], b1, acc, 0, 0, 0);
            uint2 st; st.x = pk2(acc[0], acc[1]); st.y = pk2(acc[2], acc[3]);
            *reinterpret_cast<uint2*>(kvrow + mt * 16) = st;
        }
    }
}

// ---------------- Pass B: R3-style two-pass attention, 4 threads/voxel ----------------
#define NBLK_B 13824
__global__ __launch_bounds__(256, 6) void attn4(
    const float* __restrict__ x, const float* __restrict__ qkv_w,
    const float* __restrict__ qkv_b, const float* __restrict__ out_w,
    const float* __restrict__ out_b, const float* __restrict__ rel_pos,
    const u16* __restrict__ KV, float* __restrict__ out)
{
    int bid = blockIdx.x;
    bid = (bid & 7) * (NBLK_B / 8) + (bid >> 3);
    int batch = bid / (NBLK_B / 2);
    int s0 = (bid - batch * (NBLK_B / 2)) * 64;
    int t = threadIdx.x, lane = t & 63, wv = t >> 6;
    int lo = lane & 15, hi = lane >> 4;
    int vt = t >> 2, q = t & 3;

    __shared__ u16 Lx[64 * 72];   // x bf16 tile
    __shared__ u16 Lq[64 * 72];   // Q bf16 tile -> attn-out bf16 tile
    __shared__ u16 Lr[64 * 28];   // rel-logits bf16 (raw, unscaled)

    const float* xb = x + (size_t)batch * 64 * Sd + s0;
    {   // stage: wave wv loads channels [wv*16, wv*16+16) for all 64 voxels (coalesced)
        int u = lane;
        u32 pk[8];
#pragma unroll
        for (int c2 = 0; c2 < 16; c2 += 2){
            float f0 = xb[(size_t)(wv*16 + c2) * Sd + u];
            float f1 = xb[(size_t)(wv*16 + c2 + 1) * Sd + u];
            pk[c2 >> 1] = pk2(f0, f1);
        }
#pragma unroll
        for (int k2 = 0; k2 < 2; ++k2){
            uint4 uu; uu.x = pk[k2*4+0]; uu.y = pk[k2*4+1]; uu.z = pk[k2*4+2]; uu.w = pk[k2*4+3];
            *reinterpret_cast<uint4*>(&Lx[u * 72 + wv * 16 + k2 * 8]) = uu;
        }
    }
    __syncthreads();   // cross-wave: Q-proj reads all channels

    {   // Q-projection MFMA; wave handles its 16 voxel rows -> Lq
        short8 qa[4][2];
        f32x4  qbias[4];
#pragma unroll
        for (int mt = 0; mt < 4; ++mt){
#pragma unroll
            for (int kh = 0; kh < 2; ++kh)
                qa[mt][kh] = ldfrag_w(qkv_w + (size_t)(mt*16 + lo) * 64 + kh*32 + hi*8);
            qbias[mt] = *reinterpret_cast<const f32x4*>(qkv_b + mt*16 + hi*4);
        }
        int vl = wv * 16 + lo;
        const u16* br = &Lx[vl * 72 + hi * 8];
        short8 b0 = *reinterpret_cast<const short8*>(br);
        short8 b1 = *reinterpret_cast<const short8*>(br + 32);
#pragma unroll
        for (int mt = 0; mt < 4; ++mt){
            f32x4 acc = qbias[mt];
            acc = __builtin_amdgcn_mfma_f32_16x16x32_bf16(qa[mt][0], b0, acc, 0, 0, 0);
            acc = __builtin_amdgcn_mfma_f32_16x16x32_bf16(qa[mt][1], b1, acc, 0, 0, 0);
            uint2 st; st.x = pk2(acc[0], acc[1]); st.y = pk2(acc[2], acc[3]);
            *reinterpret_cast<uint2*>(&Lq[vl * 72 + mt * 16 + hi * 4]) = st;
        }
    }

    {   // rel-logits MFMA: R(27x64 pad 32) x Q -> Lr bf16 (raw)
        short8 ra[2][2];
#pragma unroll
        for (int mt = 0; mt < 2; ++mt){
            int o = mt * 16 + lo;
#pragma unroll
            for (int kh = 0; kh < 2; ++kh){
                float f[8];
#pragma unroll
                for (int j = 0; j < 8; ++j){
                    int k = kh * 32 + hi * 8 + j;
                    f[j] = (o < 27) ? rel_pos[k * 27 + o] : 0.f;
                }
                union { short8 s; u32 u[4]; } r;
                r.u[0] = pk2(f[0], f[1]); r.u[1] = pk2(f[2], f[3]);
                r.u[2] = pk2(f[4], f[5]); r.u[3] = pk2(f[6], f[7]);
                ra[mt][kh] = r.s;
            }
        }
        int vl = wv * 16 + lo;
        const u16* br = &Lq[vl * 72 + hi * 8];
        short8 b0 = *reinterpret_cast<const short8*>(br);
        short8 b1 = *reinterpret_cast<const short8*>(br + 32);
        f32x4 a0 = {0.f, 0.f, 0.f, 0.f};
        f32x4 a1 = {0.f, 0.f, 0.f, 0.f};
        a0 = __builtin_amdgcn_mfma_f32_16x16x32_bf16(ra[0][0], b0, a0, 0, 0, 0);
        a0 = __builtin_amdgcn_mfma_f32_16x16x32_bf16(ra[0][1], b1, a0, 0, 0, 0);
        a1 = __builtin_amdgcn_mfma_f32_16x16x32_bf16(ra[1][0], b0, a1, 0, 0, 0);
        a1 = __builtin_amdgcn_mfma_f32_16x16x32_bf16(ra[1][1], b1, a1, 0, 0, 0);
        u32* Lr32 = reinterpret_cast<u32*>(Lr);
        Lr32[vl * 14 + hi * 2 + 0] = pk2(a0[0], a0[1]);
        Lr32[vl * 14 + hi * 2 + 1] = pk2(a0[2], a0[3]);
        if (hi < 3){   // rows 16..27 (slot 27 = padding, never read)
            Lr32[vl * 14 + 8 + hi * 2 + 0] = pk2(a1[0], a1[1]);
            Lr32[vl * 14 + 8 + hi * 2 + 1] = pk2(a1[2], a1[3]);
        }
    }

    // per-thread: own 16 channels of Q (scalar floats, R3-style)
    float Q[16];
    {
        const u16* qr = &Lq[vt * 72 + q * 16];
        uint4 qa0 = *reinterpret_cast<const uint4*>(qr);
        uint4 qa1 = *reinterpret_cast<const uint4*>(qr + 8);
        Q[0]  = bflo(qa0.x); Q[1]  = bfhi(qa0.x);
        Q[2]  = bflo(qa0.y); Q[3]  = bfhi(qa0.y);
        Q[4]  = bflo(qa0.z); Q[5]  = bfhi(qa0.z);
        Q[6]  = bflo(qa0.w); Q[7]  = bfhi(qa0.w);
        Q[8]  = bflo(qa1.x); Q[9]  = bfhi(qa1.x);
        Q[10] = bflo(qa1.y); Q[11] = bfhi(qa1.y);
        Q[12] = bflo(qa1.z); Q[13] = bfhi(qa1.z);
        Q[14] = bflo(qa1.w); Q[15] = bfhi(qa1.w);
    }

    int s = s0 + vt;
    int d = s / HWc; int r = s - d * HWc; int h3 = r / Wc; int w3 = r - h3 * Wc;
    const u16* kvb = KV + ((size_t)batch * Sd + (size_t)s) * 128 + q * 16;
    const u16* lr = &Lr[vt * 28];

    // ---- Phase 1: 27 K-dots (R3-style guarded), quartet shfl reduce ----
    float lg[27];
#pragma unroll
    for (int o = 0; o < 27; ++o){
        const int di = o / 9 - 1, dj = (o / 3) % 3 - 1, dk = o % 3 - 1;
        bool inb = ((unsigned)(d + di) < (unsigned)Dc) &&
                   ((unsigned)(h3 + dj) < (unsigned)Hc) &&
                   ((unsigned)(w3 + dk) < (unsigned)Wc);
        float dsum = 0.f;
        if (inb){
            const uint4* p4 = reinterpret_cast<const uint4*>(kvb + (ptrdiff_t)(di * HWc + dj * Wc + dk) * 128);
            uint4 k0 = p4[0];
            uint4 k1 = p4[1];
            float d0 = 0.f, d1 = 0.f, d2 = 0.f, d3 = 0.f;
            d0 += bflo(k0.x) * Q[0];  d1 += bfhi(k0.x) * Q[1];
            d2 += bflo(k0.y) * Q[2];  d3 += bfhi(k0.y) * Q[3];
            d0 += bflo(k0.z) * Q[4];  d1 += bfhi(k0.z) * Q[5];
            d2 += bflo(k0.w) * Q[6];  d3 += bfhi(k0.w) * Q[7];
            d0 += bflo(k1.x) * Q[8];  d1 += bfhi(k1.x) * Q[9];
            d2 += bflo(k1.y) * Q[10]; d3 += bfhi(k1.y) * Q[11];
            d0 += bflo(k1.z) * Q[12]; d1 += bfhi(k1.z) * Q[13];
            d2 += bflo(k1.w) * Q[14]; d3 += bfhi(k1.w) * Q[15];
            dsum = (d0 + d1) + (d2 + d3);
        }
        dsum += __shfl_xor(dsum, 1);
        dsum += __shfl_xor(dsum, 2);
        lg[o] = 0.125f * (dsum + __uint_as_float(((u32)lr[o]) << 16));
    }

    // softmax over 27 (R3 exact)
    float m = lg[0];
#pragma unroll
    for (int o = 1; o < 27; ++o) m = fmaxf(m, lg[o]);
    float ssum = 0.f;
#pragma unroll
    for (int o = 0; o < 27; ++o){ lg[o] = __expf(lg[o] - m); ssum += lg[o]; }
    float inv = 1.f / ssum;

    // ---- Phase 2: V accumulation (R3-style guarded) ----
    float acc[16];
#pragma unroll
    for (int c = 0; c < 16; ++c) acc[c] = 0.f;
#pragma unroll
    for (int o = 0; o < 27; ++o){
        const int di = o / 9 - 1, dj = (o / 3) % 3 - 1, dk = o % 3 - 1;
        bool inb = ((unsigned)(d + di) < (unsigned)Dc) &&
                   ((unsigned)(h3 + dj) < (unsigned)Hc) &&
                   ((unsigned)(w3 + dk) < (unsigned)Wc);
        if (!inb) continue;
        float a = lg[o] * inv;
        const uint4* p4 = reinterpret_cast<const uint4*>(kvb + (ptrdiff_t)(di * HWc + dj * Wc + dk) * 128 + 64);
        uint4 v0 = p4[0];
        uint4 v1 = p4[1];
        acc[0]  += a * bflo(v0.x); acc[1]  += a * bfhi(v0.x);
        acc[2]  += a * bflo(v0.y); acc[3]  += a * bfhi(v0.y);
        acc[4]  += a * bflo(v0.z); acc[5]  += a * bfhi(v0.z);
        acc[6]  += a * bflo(v0.w); acc[7]  += a * bfhi(v0.w);
        acc[8]  += a * bflo(v1.x); acc[9]  += a * bfhi(v1.x);
        acc[10] += a * bflo(v1.y); acc[11] += a * bfhi(v1.y);
        acc[12] += a * bflo(v1.z); acc[13] += a * bfhi(v1.z);
        acc[14] += a * bflo(v1.w); acc[15] += a * bfhi(v1.w);
    }

    // residual (coalesced fp32 re-read, after gather loop)
    {
        const float* xv = x + ((size_t)batch * 64 + q * 16) * Sd + (size_t)(s0 + vt);
#pragma unroll
        for (int c = 0; c < 16; ++c) acc[c] += xv[(size_t)c * Sd];
    }

    // write attn-out (own 16 chans) bf16 into Lq (wave-local rows)
    {
        uint4 w0, w1;
        w0.x = pk2(acc[0],  acc[1]);  w0.y = pk2(acc[2],  acc[3]);
        w0.z = pk2(acc[4],  acc[5]);  w0.w = pk2(acc[6],  acc[7]);
        w1.x = pk2(acc[8],  acc[9]);  w1.y = pk2(acc[10], acc[11]);
        w1.z = pk2(acc[12], acc[13]); w1.w = pk2(acc[14], acc[15]);
        *reinterpret_cast<uint4*>(&Lq[vt * 72 + q * 16])     = w0;
        *reinterpret_cast<uint4*>(&Lq[vt * 72 + q * 16 + 8]) = w1;
    }

    {   // out-projection MFMA (wave-local rows) -> fp32 stores
        short8 oa[4][2];
        f32x4  obias[4];
#pragma unroll
        for (int mt = 0; mt < 4; ++mt){
#pragma unroll
            for (int kh = 0; kh < 2; ++kh)
                oa[mt][kh] = ldfrag_w(out_w + (size_t)(mt*16 + lo) * 64 + kh*32 + hi*8);
            obias[mt] = *reinterpret_cast<const f32x4*>(out_b + mt*16 + hi*4);
        }
        int vl = wv * 16 + lo;
        const u16* br = &Lq[vl * 72 + hi * 8];
        short8 b0 = *reinterpret_cast<const short8*>(br);
        short8 b1 = *reinterpret_cast<const short8*>(br + 32);
#pragma unroll
        for (int mt = 0; mt < 4; ++mt){
            f32x4 a4 = obias[mt];
            a4 = __builtin_amdgcn_mfma_f32_16x16x32_bf16(oa[mt][0], b0, a4, 0, 0, 0);
            a4 = __builtin_amdgcn_mfma_f32_16x16x32_bf16(oa[mt][1], b1, a4, 0, 0, 0);
            float* op = out + ((size_t)batch * 64 + mt*16 + hi*4) * Sd + (s0 + vl);
            op[0]              = a4[0];
            op[(size_t)Sd]     = a4[1];
            op[(size_t)2*Sd]   = a4[2];
            op[(size_t)3*Sd]   = a4[3];
        }
    }
}

extern "C" void kernel_launch(void* const* d_in, const int* in_sizes, int n_in,
                              void* d_out, int out_size, void* d_ws, size_t ws_size,
                              hipStream_t stream) {
    const float* x       = (const float*)d_in[0];
    const float* qkv_w   = (const float*)d_in[1];
    const float* qkv_b   = (const float*)d_in[2];
    const float* out_w   = (const float*)d_in[3];
    const float* out_b   = (const float*)d_in[4];
    const float* rel_pos = (const float*)d_in[5];
    float* out = (float*)d_out;
    u16* KV = (u16*)d_ws;   // 884736 * 128 * 2B = 216 MB

    kv_mfma<<<NBLK_A, 256, 0, stream>>>(x, qkv_w, qkv_b, KV);
    attn4<<<NBLK_B, 256, 0, stream>>>(x, qkv_w, qkv_b, out_w, out_b,
                                      rel_pos, KV, out);
}

// Round 10
// 723.653 us; speedup vs baseline: 5.2215x; 1.2365x over previous
//
#include <hip/hip_runtime.h>
#include <hip/hip_bf16.h>

#define Sd 442368      // D*H*W
#define HWc 9216
#define Wc 96
#define Hc 96
#define Dc 48

typedef unsigned short u16;
typedef unsigned int u32;
typedef __attribute__((ext_vector_type(8))) short short8;
typedef __attribute__((ext_vector_type(4))) float f32x4;

static __device__ __forceinline__ u16 f2bf(float f){
    __hip_bfloat16 h = __float2bfloat16(f);
    return *reinterpret_cast<u16*>(&h);
}
static __device__ __forceinline__ u32 pk2(float a, float b){
    return ((u32)f2bf(b) << 16) | (u32)f2bf(a);
}
static __device__ __forceinline__ float bflo(u32 u){ return __uint_as_float(u << 16); }
static __device__ __forceinline__ float bfhi(u32 u){ return __uint_as_float(u & 0xffff0000u); }

static __device__ __forceinline__ short8 ldfrag_w(const float* p){
    float4 f0 = *reinterpret_cast<const float4*>(p);
    float4 f1 = *reinterpret_cast<const float4*>(p + 4);
    union { short8 s; u32 u[4]; } r;
    r.u[0] = pk2(f0.x, f0.y); r.u[1] = pk2(f0.z, f0.w);
    r.u[2] = pk2(f1.x, f1.y); r.u[3] = pk2(f1.z, f1.w);
    return r.s;
}

// ---------------- Pass A: K,V projection via MFMA, bf16 [vox][128] ----------------
#define NBLK_A 3456
__global__ __launch_bounds__(256, 2) void kv_mfma(
    const float* __restrict__ x, const float* __restrict__ qkv_w,
    const float* __restrict__ qkv_b, u16* __restrict__ KV)
{
    int bid = blockIdx.x;
    bid = (bid & 7) * (NBLK_A / 8) + (bid >> 3);
    int batch = bid / (NBLK_A / 2);
    int s0 = (bid - batch * (NBLK_A / 2)) * 256;
    int t = threadIdx.x, lane = t & 63, wv = t >> 6;
    int lo = lane & 15, hi = lane >> 4;
    __shared__ u16 L[256 * 72];

    const float* xb = x + (size_t)batch * 64 * Sd + s0;
    {
        u32 pk[32];
#pragma unroll
        for (int c = 0; c < 64; c += 2){
            float f0 = xb[(size_t)c * Sd + t];
            float f1 = xb[(size_t)(c + 1) * Sd + t];
            pk[c >> 1] = pk2(f0, f1);
        }
#pragma unroll
        for (int k = 0; k < 8; ++k){
            uint4 u; u.x = pk[k*4+0]; u.y = pk[k*4+1]; u.z = pk[k*4+2]; u.w = pk[k*4+3];
            *reinterpret_cast<uint4*>(&L[t * 72 + k * 8]) = u;
        }
    }
    // wave-local staging: thread t writes row t; wave reads rows [wv*64, wv*64+64)

    short8 af[8][2];
    f32x4  bias[8];
#pragma unroll
    for (int mt = 0; mt < 8; ++mt){
#pragma unroll
        for (int kh = 0; kh < 2; ++kh)
            af[mt][kh] = ldfrag_w(qkv_w + (size_t)(64 + mt*16 + lo) * 64 + kh*32 + hi*8);
        bias[mt] = *reinterpret_cast<const f32x4*>(qkv_b + 64 + mt*16 + hi*4);
    }

#pragma unroll
    for (int nt = 0; nt < 4; ++nt){
        int vl = wv * 64 + nt * 16 + lo;
        const u16* br = &L[vl * 72 + hi * 8];
        short8 b0 = *reinterpret_cast<const short8*>(br);
        short8 b1 = *reinterpret_cast<const short8*>(br + 32);
        u16* kvrow = KV + (size_t)(batch * Sd + s0 + vl) * 128 + hi * 4;
#pragma unroll
        for (int mt = 0; mt < 8; ++mt){
            f32x4 acc = bias[mt];
            acc = __builtin_amdgcn_mfma_f32_16x16x32_bf16(af[mt][0], b0, acc, 0, 0, 0);
            acc = __builtin_amdgcn_mfma_f32_16x16x32_bf16(af[mt][1], b1, acc, 0, 0, 0);
            uint2 st; st.x = pk2(acc[0], acc[1]); st.y = pk2(acc[2], acc[3]);
            *reinterpret_cast<uint2*>(kvrow + mt * 16) = st;
        }
    }
}

// ---------------- Pass B: R3 structure, in-place LDS, p[] in Lr, 2 threads/voxel ----------------
#define NBLK_B 6912
#define SCLOG 0.18033688011112042f   // 0.125 * log2(e)

__global__ __launch_bounds__(256, 4) void attn_r10(
    const float* __restrict__ x, const float* __restrict__ qkv_w,
    const float* __restrict__ qkv_b, const float* __restrict__ out_w,
    const float* __restrict__ out_b, const float* __restrict__ rel_pos,
    const u16* __restrict__ KV, float* __restrict__ out)
{
    int bid = blockIdx.x;
    bid = (bid & 7) * (NBLK_B / 8) + (bid >> 3);
    int batch = bid / (NBLK_B / 2);
    int s0 = (bid - batch * (NBLK_B / 2)) * 128;
    int t = threadIdx.x, lane = t & 63, wv = t >> 6;
    int lo = lane & 15, hi = lane >> 4;
    int vt = t >> 1, half = t & 1;

    __shared__ u16 Lx[128 * 72];   // x bf16 -> Q bf16 (in place) -> attn-out bf16
    __shared__ u16 Lr[128 * 28];   // rel-logits bf16 (raw) -> p bf16 (in place)

    const float* xb = x + (size_t)batch * 64 * Sd + s0;
    {   // stage own 32 channels of voxel vt (wave-local rows)
        u32 pk[16];
#pragma unroll
        for (int c2 = 0; c2 < 32; c2 += 2){
            float f0 = xb[(size_t)(half*32 + c2) * Sd + vt];
            float f1 = xb[(size_t)(half*32 + c2 + 1) * Sd + vt];
            pk[c2 >> 1] = pk2(f0, f1);
        }
#pragma unroll
        for (int k = 0; k < 4; ++k){
            uint4 u; u.x = pk[k*4+0]; u.y = pk[k*4+1]; u.z = pk[k*4+2]; u.w = pk[k*4+3];
            *reinterpret_cast<uint4*>(&Lx[vt * 72 + half * 32 + k * 8]) = u;
        }
    }

    {   // Q-projection MFMA; overwrite own wave's rows of Lx with Q bf16 (in place)
        short8 qa[4][2];
        f32x4  qbias[4];
#pragma unroll
        for (int mt = 0; mt < 4; ++mt){
#pragma unroll
            for (int kh = 0; kh < 2; ++kh)
                qa[mt][kh] = ldfrag_w(qkv_w + (size_t)(mt*16 + lo) * 64 + kh*32 + hi*8);
            qbias[mt] = *reinterpret_cast<const f32x4*>(qkv_b + mt*16 + hi*4);
        }
#pragma unroll
        for (int nt = 0; nt < 2; ++nt){
            int vl = wv * 32 + nt * 16 + lo;
            const u16* br = &Lx[vl * 72 + hi * 8];
            short8 b0 = *reinterpret_cast<const short8*>(br);
            short8 b1 = *reinterpret_cast<const short8*>(br + 32);
#pragma unroll
            for (int mt = 0; mt < 4; ++mt){
                f32x4 acc = qbias[mt];
                acc = __builtin_amdgcn_mfma_f32_16x16x32_bf16(qa[mt][0], b0, acc, 0, 0, 0);
                acc = __builtin_amdgcn_mfma_f32_16x16x32_bf16(qa[mt][1], b1, acc, 0, 0, 0);
                uint2 st; st.x = pk2(acc[0], acc[1]); st.y = pk2(acc[2], acc[3]);
                *reinterpret_cast<uint2*>(&Lx[vl * 72 + mt * 16 + hi * 4]) = st;
            }
        }
    }

    {   // rel-logits MFMA: R(27x64 pad 32) x Q -> Lr bf16 (raw logits)
        short8 ra[2][2];
#pragma unroll
        for (int mt = 0; mt < 2; ++mt){
            int o = mt * 16 + lo;
#pragma unroll
            for (int kh = 0; kh < 2; ++kh){
                float f[8];
#pragma unroll
                for (int j = 0; j < 8; ++j){
                    int k = kh * 32 + hi * 8 + j;
                    f[j] = (o < 27) ? rel_pos[k * 27 + o] : 0.f;
                }
                union { short8 s; u32 u[4]; } r;
                r.u[0] = pk2(f[0], f[1]); r.u[1] = pk2(f[2], f[3]);
                r.u[2] = pk2(f[4], f[5]); r.u[3] = pk2(f[6], f[7]);
                ra[mt][kh] = r.s;
            }
        }
        u32* Lr32 = reinterpret_cast<u32*>(Lr);
#pragma unroll
        for (int nt = 0; nt < 2; ++nt){
            int vl = wv * 32 + nt * 16 + lo;
            const u16* br = &Lx[vl * 72 + hi * 8];
            short8 b0 = *reinterpret_cast<const short8*>(br);
            short8 b1 = *reinterpret_cast<const short8*>(br + 32);
            f32x4 a0 = {0.f, 0.f, 0.f, 0.f};
            f32x4 a1 = {0.f, 0.f, 0.f, 0.f};
            a0 = __builtin_amdgcn_mfma_f32_16x16x32_bf16(ra[0][0], b0, a0, 0, 0, 0);
            a0 = __builtin_amdgcn_mfma_f32_16x16x32_bf16(ra[0][1], b1, a0, 0, 0, 0);
            a1 = __builtin_amdgcn_mfma_f32_16x16x32_bf16(ra[1][0], b0, a1, 0, 0, 0);
            a1 = __builtin_amdgcn_mfma_f32_16x16x32_bf16(ra[1][1], b1, a1, 0, 0, 0);
            Lr32[vl * 14 + hi * 2 + 0] = pk2(a0[0], a0[1]);
            Lr32[vl * 14 + hi * 2 + 1] = pk2(a0[2], a0[3]);
            if (hi < 3){   // rows 16..27 (row 27 slot = MFMA zero pad, never read)
                Lr32[vl * 14 + 8 + hi * 2 + 0] = pk2(a1[0], a1[1]);
                Lr32[vl * 14 + 8 + hi * 2 + 1] = pk2(a1[2], a1[3]);
            }
        }
    }

    // per-thread: own half of Q as scalar floats (R3-style)
    float Q[32];
#pragma unroll
    for (int k = 0; k < 4; ++k){
        uint4 q4 = *reinterpret_cast<const uint4*>(&Lx[vt * 72 + half * 32 + k * 8]);
        Q[k*8+0] = bflo(q4.x); Q[k*8+1] = bfhi(q4.x);
        Q[k*8+2] = bflo(q4.y); Q[k*8+3] = bfhi(q4.y);
        Q[k*8+4] = bflo(q4.z); Q[k*8+5] = bfhi(q4.z);
        Q[k*8+6] = bflo(q4.w); Q[k*8+7] = bfhi(q4.w);
    }

    int s = s0 + vt;
    int d = s / HWc; int r = s - d * HWc; int h3 = r / Wc; int w3 = r - h3 * Wc;
    // u16 units: voxel row = 128 u16 (64 K + 64 V). This thread's K half = channels [half*32, half*32+32).
    const u16* kvb = KV + ((size_t)batch * Sd + (size_t)s) * 128 + half * 32;
    u16* lr = &Lr[vt * 28];

    // ---- Phase 1: 27 guarded K-dots -> p = exp2(SCLOG*(dot+rel)), p stored into Lr slot ----
    float l = 0.f;
#pragma unroll
    for (int o = 0; o < 27; ++o){
        const int di = o / 9 - 1, dj = (o / 3) % 3 - 1, dk = o % 3 - 1;
        bool inb = ((unsigned)(d + di) < (unsigned)Dc) &&
                   ((unsigned)(h3 + dj) < (unsigned)Hc) &&
                   ((unsigned)(w3 + dk) < (unsigned)Wc);
        float dsum = 0.f;
        if (inb){
            const uint4* p4 = reinterpret_cast<const uint4*>(kvb + (ptrdiff_t)(di * HWc + dj * Wc + dk) * 128);
            uint4 k0 = p4[0];
            uint4 k1 = p4[1];
            uint4 k2 = p4[2];
            uint4 k3 = p4[3];
            float d0 = 0.f, d1 = 0.f, d2 = 0.f, d3 = 0.f;
            d0 += bflo(k0.x) * Q[0];  d1 += bfhi(k0.x) * Q[1];
            d2 += bflo(k0.y) * Q[2];  d3 += bfhi(k0.y) * Q[3];
            d0 += bflo(k0.z) * Q[4];  d1 += bfhi(k0.z) * Q[5];
            d2 += bflo(k0.w) * Q[6];  d3 += bfhi(k0.w) * Q[7];
            d0 += bflo(k1.x) * Q[8];  d1 += bfhi(k1.x) * Q[9];
            d2 += bflo(k1.y) * Q[10]; d3 += bfhi(k1.y) * Q[11];
            d0 += bflo(k1.z) * Q[12]; d1 += bfhi(k1.z) * Q[13];
            d2 += bflo(k1.w) * Q[14]; d3 += bfhi(k1.w) * Q[15];
            d0 += bflo(k2.x) * Q[16]; d1 += bfhi(k2.x) * Q[17];
            d2 += bflo(k2.y) * Q[18]; d3 += bfhi(k2.y) * Q[19];
            d0 += bflo(k2.z) * Q[20]; d1 += bfhi(k2.z) * Q[21];
            d2 += bflo(k2.w) * Q[22]; d3 += bfhi(k2.w) * Q[23];
            d0 += bflo(k3.x) * Q[24]; d1 += bfhi(k3.x) * Q[25];
            d2 += bflo(k3.y) * Q[26]; d3 += bfhi(k3.y) * Q[27];
            d0 += bflo(k3.z) * Q[28]; d1 += bfhi(k3.z) * Q[29];
            d2 += bflo(k3.w) * Q[30]; d3 += bfhi(k3.w) * Q[31];
            dsum = (d0 + d1) + (d2 + d3);
        }
        dsum += __shfl_xor(dsum, 1);
        float lg = (dsum + __uint_as_float(((u32)lr[o]) << 16)) * SCLOG;
        float p = __builtin_amdgcn_exp2f(lg);
        l += p;
        lr[o] = f2bf(p);   // both lanes of pair write identical value (wave-local, in-order)
    }
    float inv = 1.f / l;

    // ---- Phase 2: guarded V accumulation with weights from Lr ----
    float acc[32];
#pragma unroll
    for (int c = 0; c < 32; ++c) acc[c] = 0.f;
#pragma unroll
    for (int o = 0; o < 27; ++o){
        const int di = o / 9 - 1, dj = (o / 3) % 3 - 1, dk = o % 3 - 1;
        bool inb = ((unsigned)(d + di) < (unsigned)Dc) &&
                   ((unsigned)(h3 + dj) < (unsigned)Hc) &&
                   ((unsigned)(w3 + dk) < (unsigned)Wc);
        if (!inb) continue;
        float a = __uint_as_float(((u32)lr[o]) << 16) * inv;
        const uint4* p4 = reinterpret_cast<const uint4*>(kvb + (ptrdiff_t)(di * HWc + dj * Wc + dk) * 128 + 64);
        uint4 v0 = p4[0];
        uint4 v1 = p4[1];
        uint4 v2 = p4[2];
        uint4 v3 = p4[3];
        acc[0]  += a * bflo(v0.x); acc[1]  += a * bfhi(v0.x);
        acc[2]  += a * bflo(v0.y); acc[3]  += a * bfhi(v0.y);
        acc[4]  += a * bflo(v0.z); acc[5]  += a * bfhi(v0.z);
        acc[6]  += a * bflo(v0.w); acc[7]  += a * bfhi(v0.w);
        acc[8]  += a * bflo(v1.x); acc[9]  += a * bfhi(v1.x);
        acc[10] += a * bflo(v1.y); acc[11] += a * bfhi(v1.y);
        acc[12] += a * bflo(v1.z); acc[13] += a * bfhi(v1.z);
        acc[14] += a * bflo(v1.w); acc[15] += a * bfhi(v1.w);
        acc[16] += a * bflo(v2.x); acc[17] += a * bfhi(v2.x);
        acc[18] += a * bflo(v2.y); acc[19] += a * bfhi(v2.y);
        acc[20] += a * bflo(v2.z); acc[21] += a * bfhi(v2.z);
        acc[22] += a * bflo(v2.w); acc[23] += a * bfhi(v2.w);
        acc[24] += a * bflo(v3.x); acc[25] += a * bfhi(v3.x);
        acc[26] += a * bflo(v3.y); acc[27] += a * bfhi(v3.y);
        acc[28] += a * bflo(v3.z); acc[29] += a * bfhi(v3.z);
        acc[30] += a * bflo(v3.w); acc[31] += a * bfhi(v3.w);
    }

    // residual: coalesced fp32 re-read of x
    {
        const float* xv = x + ((size_t)batch * 64 + half * 32) * Sd + (size_t)(s0 + vt);
#pragma unroll
        for (int c = 0; c < 32; ++c) acc[c] += xv[(size_t)c * Sd];
    }

    // write attn-out (own half) bf16 into Lx (own wave's rows)
#pragma unroll
    for (int k = 0; k < 4; ++k){
        uint4 u;
        u.x = pk2(acc[k*8+0], acc[k*8+1]); u.y = pk2(acc[k*8+2], acc[k*8+3]);
        u.z = pk2(acc[k*8+4], acc[k*8+5]); u.w = pk2(acc[k*8+6], acc[k*8+7]);
        *reinterpret_cast<uint4*>(&Lx[vt * 72 + half * 32 + k * 8]) = u;
    }

    {   // out-projection MFMA -> fp32 stores
        short8 oa[4][2];
        f32x4  obias[4];
#pragma unroll
        for (int mt = 0; mt < 4; ++mt){
#pragma unroll
            for (int kh = 0; kh < 2; ++kh)
                oa[mt][kh] = ldfrag_w(out_w + (size_t)(mt*16 + lo) * 64 + kh*32 + hi*8);
            obias[mt] = *reinterpret_cast<const f32x4*>(out_b + mt*16 + hi*4);
        }
#pragma unroll
        for (int nt = 0; nt < 2; ++nt){
            int vl = wv * 32 + nt * 16 + lo;
            const u16* br = &Lx[vl * 72 + hi * 8];
            short8 b0 = *reinterpret_cast<const short8*>(br);
            short8 b1 = *reinterpret_cast<const short8*>(br + 32);
#pragma unroll
            for (int mt = 0; mt < 4; ++mt){
                f32x4 a4 = obias[mt];
                a4 = __builtin_amdgcn_mfma_f32_16x16x32_bf16(oa[mt][0], b0, a4, 0, 0, 0);
                a4 = __builtin_amdgcn_mfma_f32_16x16x32_bf16(oa[mt][1], b1, a4, 0, 0, 0);
                float* op = out + ((size_t)batch * 64 + mt*16 + hi*4) * Sd + (s0 + vl);
                op[0]              = a4[0];
                op[(size_t)Sd]     = a4[1];
                op[(size_t)2*Sd]   = a4[2];
                op[(size_t)3*Sd]   = a4[3];
            }
        }
    }
}

extern "C" void kernel_launch(void* const* d_in, const int* in_sizes, int n_in,
                              void* d_out, int out_size, void* d_ws, size_t ws_size,
                              hipStream_t stream) {
    const float* x       = (const float*)d_in[0];
    const float* qkv_w   = (const float*)d_in[1];
    const float* qkv_b   = (const float*)d_in[2];
    const float* out_w   = (const float*)d_in[3];
    const float* out_b   = (const float*)d_in[4];
    const float* rel_pos = (const float*)d_in[5];
    float* out = (float*)d_out;
    u16* KV = (u16*)d_ws;   // 884736 * 128 * 2B = 216 MB

    kv_mfma<<<NBLK_A, 256, 0, stream>>>(x, qkv_w, qkv_b, KV);
    attn_r10<<<NBLK_B, 256, 0, stream>>>(x, qkv_w, qkv_b, out_w, out_b,
                                         rel_pos, KV, out);
}